// Round 11
// baseline (103.963 us; speedup 1.0000x reference)
//
#include <hip/hip_runtime.h>

#define POS_IN 63
#define HID 128
#define TOTAL 8789
#define NB 32
#define NPTS 65536

#define PB_OFF 8064
#define SW_OFF 8192
#define SB_OFF 8320
#define CW_OFF 8321
#define CB_OFF 8786

#define THREADS 512
#define WAVES 8
#define BLOCKS_PER_BATCH 16
#define PTS_PER_BLOCK (NPTS / BLOCKS_PER_BATCH)   /* 4096 */
#define ITERS (PTS_PER_BLOCK / (WAVES * 64))      /* 8 */

typedef __attribute__((ext_vector_type(8))) short s16x8;
typedef __attribute__((ext_vector_type(4))) float f32x4;
typedef __bf16 bf16x2 __attribute__((ext_vector_type(2)));

// f32 -> bf16 RNE, integer path (setup only; proven R2)
__device__ __forceinline__ unsigned short f2bf(float v) {
    unsigned u = __builtin_bit_cast(unsigned, v);
    unsigned r = 0x7fffu + ((u >> 16) & 1u);
    return (unsigned short)((u + r) >> 16);
}
// hot-path pack: native __bf16 casts -> v_cvt_pk_bf16_f32 (proven R6-R10)
__device__ __forceinline__ unsigned pk2(float a, float b) {
    bf16x2 v;
    v[0] = (__bf16)a;
    v[1] = (__bf16)b;
    return __builtin_bit_cast(unsigned, v);
}

// 512-thread blocks: test whether the stubborn 8-waves/CU ceiling is a
// per-CU BLOCK cap (2 blocks/CU observed for every 256-thread config,
// R2-R10). If so, 8-wave blocks double resident waves. No min-waves arg
// ((256,4) mis-executed, R3/R4).
__global__ __launch_bounds__(THREADS) void nerf_mlp_kernel(
        const float* __restrict__ params,
        const float* __restrict__ points,
        const float* __restrict__ dirs,
        float* __restrict__ out)
{
    // LDS: [0,65536) per-wave enc bufs (8KB x 8), aliased at start by pw
    // stage ([128][72] ushort = 18432B). [65536,73728) per-wave cp bufs
    // (1KB each: [64pt][16B] f32 color partials). 72KB -> 2 blocks/CU.
    __shared__ __align__(16) unsigned char smem[73728];
    unsigned short* stage = (unsigned short*)smem;

    const int tid = threadIdx.x;
    const int lane = tid & 63;
    const int wid = tid >> 6;
    const int b = blockIdx.y;
    const float* P = params + (size_t)b * TOTAL;

    // ---- stage pw (128x63) as bf16, row stride 72; k=63 column = layer-1
    // bias (bias-in-K: e[63]=1.0). Proven R6-R10.
    for (int idx = tid; idx < 8064; idx += THREADS) {
        int n = idx / 63;
        int k = idx - n * 63;
        stage[n * 72 + k] = f2bf(P[idx]);
        if (k == 0) stage[n * 72 + 63] = f2bf(P[PB_OFF + n]);
    }
    __syncthreads();

    const int c = lane & 15;   // tile col: point-in-tile (and o for layer-2)
    const int kg = lane >> 4;  // k-group 0..3

    // ---- 16 persistent layer-1 fragments: lane holds pw[n=nt*16+c][k slice]
    s16x8 wB[8][2];
    #pragma unroll
    for (int nt = 0; nt < 8; ++nt) {
        #pragma unroll
        for (int kh = 0; kh < 2; ++kh) {
            int n = nt * 16 + c;
            int k = kh * 32 + kg * 8;
            uint4 raw = *(const uint4*)&stage[n * 72 + k];
            wB[nt][kh] = __builtin_bit_cast(s16x8, raw);
        }
    }

    // ---- layer-2 h-chunk B frags (16 VGPR), PERMUTED to match A2's local
    // packing (proven R10): physical slot (kg,e) = logical h
    // (e<4 ? 2m : 2m+1)*16 + kg*4 + (e&3). o = c: 0..2 color, 3 sigma.
    s16x8 wB2h[4];
    #pragma unroll
    for (int m = 0; m < 4; ++m) {
        uint4 dd = make_uint4(0u, 0u, 0u, 0u);
        if (c < 4) {
            const int base = (c == 3) ? SW_OFF : (CW_OFF + c * 155);
            const int b0 = base + 32 * m + kg * 4;
            dd.x = pk2(P[b0 + 0],  P[b0 + 1]);
            dd.y = pk2(P[b0 + 2],  P[b0 + 3]);
            dd.z = pk2(P[b0 + 16], P[b0 + 17]);
            dd.w = pk2(P[b0 + 18], P[b0 + 19]);
        }
        wB2h[m] = __builtin_bit_cast(s16x8, dd);
    }
    const float cbias = P[c < 3 ? (CB_OFF + c) : SB_OFF];

    __syncthreads();   // stage area -> enc buffers

    unsigned char* encb = smem + wid * 8192;            // [kq][pt][16B]
    float* cpb = (float*)(smem + 65536 + wid * 1024);   // [64pt][4 f32]

    const size_t bpts = (size_t)b * NPTS;
    const int n0b = blockIdx.x * PTS_PER_BLOCK;

    for (int it = 0; it < ITERS; ++it) {
        const int n0 = n0b + it * (WAVES * 64) + wid * 64;
        const int p = n0 + lane;

        const float* pp = points + (bpts + p) * 3;
        float x = pp[0], y = pp[1], z = pp[2];
        const float* dd = dirs + (bpts + p) * 3;
        float dx = dd[0], dy = dd[1], dz = dd[2];

        // ---- dir encoding folded into per-point color partials (f32,
        // SGPR weights; R7-proven path)
        float cp0 = 0.f, cp1 = 0.f, cp2 = 0.f;
        #pragma unroll
        for (int i = 0; i < 3; ++i) {
            float v = (i == 0) ? dx : (i == 1) ? dy : dz;
            cp0 = fmaf(v, P[CW_OFF + 128 + i], cp0);
            cp1 = fmaf(v, P[CW_OFF + 155 + 128 + i], cp1);
            cp2 = fmaf(v, P[CW_OFF + 310 + 128 + i], cp2);
            float s = __sinf(v), co = __cosf(v);
            #pragma unroll
            for (int f = 0; f < 4; ++f) {
                if (f > 0) {
                    float ns = 2.f * s * co;
                    float nc = 1.f - 2.f * s * s;
                    s = ns; co = nc;
                }
                int si = 128 + 3 + i * 4 + f;
                int ci = 128 + 15 + i * 4 + f;
                cp0 = fmaf(s, P[CW_OFF + si], cp0);
                cp1 = fmaf(s, P[CW_OFF + 155 + si], cp1);
                cp2 = fmaf(s, P[CW_OFF + 310 + si], cp2);
                cp0 = fmaf(co, P[CW_OFF + ci], cp0);
                cp1 = fmaf(co, P[CW_OFF + 155 + ci], cp1);
                cp2 = fmaf(co, P[CW_OFF + 310 + ci], cp2);
            }
        }
        *(float4*)(cpb + lane * 4) = make_float4(cp0, cp1, cp2, 0.f);

        // ---- positional encoding (63 + bias slot), angle-doubling sincos
        float e[64];
        e[0] = x; e[1] = y; e[2] = z; e[63] = 1.0f;
        #pragma unroll
        for (int i = 0; i < 3; ++i) {
            float v = (i == 0) ? x : (i == 1) ? y : z;
            float s = __sinf(v), co = __cosf(v);
            e[3 + i * 10] = s; e[33 + i * 10] = co;
            #pragma unroll
            for (int f = 1; f < 10; ++f) {
                float ns = 2.f * s * co;
                float nc = 1.f - 2.f * s * s;
                s = ns; co = nc;
                e[3 + i * 10 + f] = s;
                e[33 + i * 10 + f] = co;
            }
        }
        #pragma unroll
        for (int kq = 0; kq < 8; ++kq) {
            uint4 q;
            q.x = pk2(e[kq * 8 + 0], e[kq * 8 + 1]);
            q.y = pk2(e[kq * 8 + 2], e[kq * 8 + 3]);
            q.z = pk2(e[kq * 8 + 4], e[kq * 8 + 5]);
            q.w = pk2(e[kq * 8 + 6], e[kq * 8 + 7]);
            *(uint4*)(encb + kq * 1024 + lane * 16) = q;
        }

        float* outp = out + (bpts + n0) * 4;

        // ---- 4 m-tiles of 16 points
        #pragma unroll
        for (int t = 0; t < 4; ++t) {
            uint4 a0r = *(const uint4*)(encb + kg * 1024 + (t * 16 + c) * 16);
            uint4 a1r = *(const uint4*)(encb + (4 + kg) * 1024 + (t * 16 + c) * 16);
            s16x8 A0 = __builtin_bit_cast(s16x8, a0r);
            s16x8 A1 = __builtin_bit_cast(s16x8, a1r);

            // layer-1 (swapped: D[h][pt]) fused with layer-2 via permuted-B.
            // acc2 split into two parallel chains (latency: depth 9 -> 5).
            f32x4 acc2a = (f32x4){0.f, 0.f, 0.f, 0.f};
            f32x4 acc2b = (f32x4){0.f, 0.f, 0.f, 0.f};
            #pragma unroll
            for (int m = 0; m < 4; ++m) {
                f32x4 accA = (f32x4){0.f, 0.f, 0.f, 0.f};
                f32x4 accB = (f32x4){0.f, 0.f, 0.f, 0.f};
                accA = __builtin_amdgcn_mfma_f32_16x16x32_bf16(wB[2 * m][0], A0, accA, 0, 0, 0);
                accA = __builtin_amdgcn_mfma_f32_16x16x32_bf16(wB[2 * m][1], A1, accA, 0, 0, 0);
                accB = __builtin_amdgcn_mfma_f32_16x16x32_bf16(wB[2 * m + 1][0], A0, accB, 0, 0, 0);
                accB = __builtin_amdgcn_mfma_f32_16x16x32_bf16(wB[2 * m + 1][1], A1, accB, 0, 0, 0);
                uint4 dd2;
                dd2.x = pk2(fmaxf(accA[0], 0.f), fmaxf(accA[1], 0.f));
                dd2.y = pk2(fmaxf(accA[2], 0.f), fmaxf(accA[3], 0.f));
                dd2.z = pk2(fmaxf(accB[0], 0.f), fmaxf(accB[1], 0.f));
                dd2.w = pk2(fmaxf(accB[2], 0.f), fmaxf(accB[3], 0.f));
                s16x8 A2 = __builtin_bit_cast(s16x8, dd2);
                if (m & 1)
                    acc2b = __builtin_amdgcn_mfma_f32_16x16x32_bf16(A2, wB2h[m], acc2b, 0, 0, 0);
                else
                    acc2a = __builtin_amdgcn_mfma_f32_16x16x32_bf16(A2, wB2h[m], acc2a, 0, 0, 0);
            }

            // D2: lane (c,kg) reg j = (pt = t*16+kg*4+j, o = c), valid c<4.
            if (c < 4) {
                #pragma unroll
                for (int j = 0; j < 4; ++j) {
                    int pt = t * 16 + kg * 4 + j;
                    float v = acc2a[j] + acc2b[j] + cbias;
                    if (c < 3) v += cpb[pt * 4 + c];   // dir-branch color part
                    float sig = 1.f / (1.f + __expf(-v));
                    v = (c < 3) ? sig : v;             // sigmoid on color only
                    outp[t * 64 + kg * 16 + j * 4 + c] = v;
                }
            }
        }
    }
}

extern "C" void kernel_launch(void* const* d_in, const int* in_sizes, int n_in,
                              void* d_out, int out_size, void* d_ws, size_t ws_size,
                              hipStream_t stream) {
    const float* params = (const float*)d_in[0];
    const float* points = (const float*)d_in[1];
    const float* dirs   = (const float*)d_in[2];
    float* out = (float*)d_out;
    dim3 grid(BLOCKS_PER_BATCH, NB);
    nerf_mlp_kernel<<<grid, THREADS, 0, stream>>>(params, points, dirs, out);
}

// Round 13
// 94.966 us; speedup vs baseline: 1.0947x; 1.0947x over previous
//
#include <hip/hip_runtime.h>

#define POS_IN 63
#define HID 128
#define TOTAL 8789
#define NB 32
#define NPTS 65536

#define PB_OFF 8064
#define SW_OFF 8192
#define SB_OFF 8320
#define CW_OFF 8321
#define CB_OFF 8786

#define BLOCKS_PER_BATCH 16
#define PTS_PER_BLOCK (NPTS / BLOCKS_PER_BATCH) /* 4096 */
#define ITERS (PTS_PER_BLOCK / 256)             /* 16 */

typedef __attribute__((ext_vector_type(8))) short s16x8;
typedef __attribute__((ext_vector_type(4))) float f32x4;
typedef __attribute__((ext_vector_type(2))) float f32x2;
typedef __bf16 bf16x2 __attribute__((ext_vector_type(2)));

// f32 -> bf16 RNE, integer path (setup only; proven R2)
__device__ __forceinline__ unsigned short f2bf(float v) {
    unsigned u = __builtin_bit_cast(unsigned, v);
    unsigned r = 0x7fffu + ((u >> 16) & 1u);
    return (unsigned short)((u + r) >> 16);
}
// hot-path pack: native __bf16 casts -> v_cvt_pk_bf16_f32 (proven R6-R11)
__device__ __forceinline__ unsigned pk2(float a, float b) {
    bf16x2 v;
    v[0] = (__bf16)a;
    v[1] = (__bf16)b;
    return __builtin_bit_cast(unsigned, v);
}

// __launch_bounds__(256) only — (256,4) mis-executes (R3/R4).
// Base = R10 (proven twice, absmax 0.015625). Additions this round:
// packed-f32 trig (VOP3P), global prefetch, acc2 chain split.
__global__ __launch_bounds__(256) void nerf_mlp_kernel(
        const float* __restrict__ params,
        const float* __restrict__ points,
        const float* __restrict__ dirs,
        float* __restrict__ out)
{
    // LDS: [0,32768) per-wave enc bufs (8KB), aliased at start by pw stage
    // ([128][72] ushort = 18432B). [32768,49152) per-wave dir bufs (4KB).
    __shared__ __align__(16) unsigned char smem[49152];
    unsigned short* stage = (unsigned short*)smem;

    const int tid = threadIdx.x;
    const int lane = tid & 63;
    const int wid = tid >> 6;
    const int b = blockIdx.y;
    const float* P = params + (size_t)b * TOTAL;

    // ---- stage pw (128x63) as bf16, row stride 72; k=63 column = layer-1
    // bias (bias-in-K: e[63]=1.0). Proven R6-R11.
    for (int idx = tid; idx < 8064; idx += 256) {
        int n = idx / 63;
        int k = idx - n * 63;
        stage[n * 72 + k] = f2bf(P[idx]);
        if (k == 0) stage[n * 72 + 63] = f2bf(P[PB_OFF + n]);
    }
    __syncthreads();

    const int c = lane & 15;   // tile col: point-in-tile (and o for layer-2)
    const int kg = lane >> 4;  // k-group 0..3

    // ---- 16 persistent layer-1 fragments: lane holds pw[n=nt*16+c][k slice]
    s16x8 wB[8][2];
    #pragma unroll
    for (int nt = 0; nt < 8; ++nt) {
        #pragma unroll
        for (int kh = 0; kh < 2; ++kh) {
            int n = nt * 16 + c;
            int k = kh * 32 + kg * 8;
            uint4 raw = *(const uint4*)&stage[n * 72 + k];
            wB[nt][kh] = __builtin_bit_cast(s16x8, raw);
        }
    }

    // ---- layer-2 h-chunk B frags (16 VGPR), PERMUTED to match A2's local
    // packing (proven R10/R11): physical slot (kg,e) = logical h
    // (e<4 ? 2m : 2m+1)*16 + kg*4 + (e&3). o = c: 0..2 color, 3 sigma.
    s16x8 wB2h[4];
    #pragma unroll
    for (int m = 0; m < 4; ++m) {
        uint4 dd = make_uint4(0u, 0u, 0u, 0u);
        if (c < 4) {
            const int base = (c == 3) ? SW_OFF : (CW_OFF + c * 155);
            const int b0 = base + 32 * m + kg * 4;
            dd.x = pk2(P[b0 + 0],  P[b0 + 1]);
            dd.y = pk2(P[b0 + 2],  P[b0 + 3]);
            dd.z = pk2(P[b0 + 16], P[b0 + 17]);
            dd.w = pk2(P[b0 + 18], P[b0 + 19]);
        }
        wB2h[m] = __builtin_bit_cast(s16x8, dd);
    }
    // ---- dir+bias chunk B frag (4 VGPR): k_loc = kg*8+e; k_loc<27 -> dir
    // weights cw[o][128+k_loc] (zero for sigma row), k_loc==27 -> bias.
    s16x8 wB2d;
    {
        float vals[8];
        #pragma unroll
        for (int e = 0; e < 8; ++e) {
            int k_loc = kg * 8 + e;
            float v = 0.f;
            if (c < 3) {
                if (k_loc < 27)       v = P[CW_OFF + c * 155 + 128 + k_loc];
                else if (k_loc == 27) v = P[CB_OFF + c];
            } else if (c == 3) {
                if (k_loc == 27)      v = P[SB_OFF];
            }
            vals[e] = v;
        }
        uint4 dd;
        dd.x = pk2(vals[0], vals[1]);
        dd.y = pk2(vals[2], vals[3]);
        dd.z = pk2(vals[4], vals[5]);
        dd.w = pk2(vals[6], vals[7]);
        wB2d = __builtin_bit_cast(s16x8, dd);
    }
    __syncthreads();   // stage area -> enc buffers

    unsigned char* encb = smem + wid * 8192;            // [kq][pt][16B]
    unsigned char* dirb = smem + 32768 + wid * 4096;    // [kq2][pt][16B]

    const size_t bpts = (size_t)b * NPTS;
    const int n0b = blockIdx.x * PTS_PER_BLOCK;

    // preload iter 0's point/dir (prefetch pipeline)
    float x, y, z, dx, dy, dz;
    {
        const int p0 = n0b + wid * 64 + lane;
        const float* pp = points + (bpts + p0) * 3;
        const float* dd = dirs + (bpts + p0) * 3;
        x = pp[0]; y = pp[1]; z = pp[2];
        dx = dd[0]; dy = dd[1]; dz = dd[2];
    }

    for (int it = 0; it < ITERS; ++it) {
        const int n0 = n0b + it * 256 + wid * 64;  // this wave's 64-pt chunk
        const int p = n0 + lane;

        // ---- dir encoding -> d[32] (trig packed: x,y axes as float2)
        float d[32];
        d[0] = dx; d[1] = dy; d[2] = dz;
        d[27] = 1.0f; d[28] = 0.f; d[29] = 0.f; d[30] = 0.f; d[31] = 0.f;
        {
            f32x2 s2, c2;
            s2[0] = __sinf(dx); s2[1] = __sinf(dy);
            c2[0] = __cosf(dx); c2[1] = __cosf(dy);
            float sz = __sinf(dz), cz = __cosf(dz);
            d[3] = s2[0]; d[7] = s2[1]; d[11] = sz;
            d[15] = c2[0]; d[19] = c2[1]; d[23] = cz;
            #pragma unroll
            for (int f = 1; f < 4; ++f) {
                f32x2 ns = 2.f * s2 * c2;
                f32x2 nc = 1.f - 2.f * s2 * s2;
                s2 = ns; c2 = nc;
                float nsz = 2.f * sz * cz;
                float ncz = 1.f - 2.f * sz * sz;
                sz = nsz; cz = ncz;
                d[3 + f] = s2[0]; d[7 + f] = s2[1]; d[11 + f] = sz;
                d[15 + f] = c2[0]; d[19 + f] = c2[1]; d[23 + f] = cz;
            }
        }
        #pragma unroll
        for (int kq = 0; kq < 4; ++kq) {
            uint4 q;
            q.x = pk2(d[kq * 8 + 0], d[kq * 8 + 1]);
            q.y = pk2(d[kq * 8 + 2], d[kq * 8 + 3]);
            q.z = pk2(d[kq * 8 + 4], d[kq * 8 + 5]);
            q.w = pk2(d[kq * 8 + 6], d[kq * 8 + 7]);
            *(uint4*)(dirb + kq * 1024 + lane * 16) = q;
        }

        // ---- positional encoding (trig packed: x,y axes as float2)
        float e[64];
        e[0] = x; e[1] = y; e[2] = z; e[63] = 1.0f;
        {
            f32x2 s2, c2;
            s2[0] = __sinf(x); s2[1] = __sinf(y);
            c2[0] = __cosf(x); c2[1] = __cosf(y);
            float sz = __sinf(z), cz = __cosf(z);
            e[3] = s2[0]; e[13] = s2[1]; e[23] = sz;
            e[33] = c2[0]; e[43] = c2[1]; e[53] = cz;
            #pragma unroll
            for (int f = 1; f < 10; ++f) {
                f32x2 ns = 2.f * s2 * c2;
                f32x2 nc = 1.f - 2.f * s2 * s2;
                s2 = ns; c2 = nc;
                float nsz = 2.f * sz * cz;
                float ncz = 1.f - 2.f * sz * sz;
                sz = nsz; cz = ncz;
                e[3 + f] = s2[0]; e[13 + f] = s2[1]; e[23 + f] = sz;
                e[33 + f] = c2[0]; e[43 + f] = c2[1]; e[53 + f] = cz;
            }
        }
        #pragma unroll
        for (int kq = 0; kq < 8; ++kq) {
            uint4 q;
            q.x = pk2(e[kq * 8 + 0], e[kq * 8 + 1]);
            q.y = pk2(e[kq * 8 + 2], e[kq * 8 + 3]);
            q.z = pk2(e[kq * 8 + 4], e[kq * 8 + 5]);
            q.w = pk2(e[kq * 8 + 6], e[kq * 8 + 7]);
            *(uint4*)(encb + kq * 1024 + lane * 16) = q;
        }

        // ---- prefetch next iter's point/dir (hides HBM latency under the
        // tile compute below; consumed at loop end)
        float nx = x, ny = y, nz = z, ndx = dx, ndy = dy, ndz = dz;
        if (it + 1 < ITERS) {
            const float* pn = points + (bpts + p + 256) * 3;
            const float* dn = dirs + (bpts + p + 256) * 3;
            nx = pn[0]; ny = pn[1]; nz = pn[2];
            ndx = dn[0]; ndy = dn[1]; ndz = dn[2];
        }

        float* outp = out + (bpts + n0) * 4;

        // ---- 4 m-tiles of 16 points
        #pragma unroll
        for (int t = 0; t < 4; ++t) {
            uint4 a0r = *(const uint4*)(encb + kg * 1024 + (t * 16 + c) * 16);
            uint4 a1r = *(const uint4*)(encb + (4 + kg) * 1024 + (t * 16 + c) * 16);
            s16x8 A0 = __builtin_bit_cast(s16x8, a0r);
            s16x8 A1 = __builtin_bit_cast(s16x8, a1r);

            // dir+bias chunk -> chain a; layer-2 h-chunks split across two
            // parallel chains (depth 5 -> 3)
            uint4 adr = *(const uint4*)(dirb + kg * 1024 + (t * 16 + c) * 16);
            s16x8 A2d = __builtin_bit_cast(s16x8, adr);
            f32x4 acc2a = (f32x4){0.f, 0.f, 0.f, 0.f};
            f32x4 acc2b = (f32x4){0.f, 0.f, 0.f, 0.f};
            acc2a = __builtin_amdgcn_mfma_f32_16x16x32_bf16(A2d, wB2d, acc2a, 0, 0, 0);

            // layer-1 (swapped: D[h][pt], pt = t*16+c on lane&15) fused with
            // layer-2 h-chunks via permuted-B (proven R10)
            #pragma unroll
            for (int m = 0; m < 4; ++m) {
                f32x4 accA = (f32x4){0.f, 0.f, 0.f, 0.f};
                f32x4 accB = (f32x4){0.f, 0.f, 0.f, 0.f};
                accA = __builtin_amdgcn_mfma_f32_16x16x32_bf16(wB[2 * m][0], A0, accA, 0, 0, 0);
                accA = __builtin_amdgcn_mfma_f32_16x16x32_bf16(wB[2 * m][1], A1, accA, 0, 0, 0);
                accB = __builtin_amdgcn_mfma_f32_16x16x32_bf16(wB[2 * m + 1][0], A0, accB, 0, 0, 0);
                accB = __builtin_amdgcn_mfma_f32_16x16x32_bf16(wB[2 * m + 1][1], A1, accB, 0, 0, 0);
                uint4 dd2;
                dd2.x = pk2(fmaxf(accA[0], 0.f), fmaxf(accA[1], 0.f));
                dd2.y = pk2(fmaxf(accA[2], 0.f), fmaxf(accA[3], 0.f));
                dd2.z = pk2(fmaxf(accB[0], 0.f), fmaxf(accB[1], 0.f));
                dd2.w = pk2(fmaxf(accB[2], 0.f), fmaxf(accB[3], 0.f));
                s16x8 A2 = __builtin_bit_cast(s16x8, dd2);
                if (m & 1)
                    acc2b = __builtin_amdgcn_mfma_f32_16x16x32_bf16(A2, wB2h[m], acc2b, 0, 0, 0);
                else
                    acc2a = __builtin_amdgcn_mfma_f32_16x16x32_bf16(A2, wB2h[m], acc2a, 0, 0, 0);
            }

            // D2: lane (c,kg) reg j = (pt = t*16+kg*4+j, o = c), valid c<4.
            if (c < 4) {
                #pragma unroll
                for (int j = 0; j < 4; ++j) {
                    float v = acc2a[j] + acc2b[j];
                    float sig = 1.f / (1.f + __expf(-v));
                    v = (c < 3) ? sig : v;      // sigmoid on color only
                    outp[t * 64 + kg * 16 + j * 4 + c] = v;
                }
            }
        }

        x = nx; y = ny; z = nz; dx = ndx; dy = ndy; dz = ndz;
    }
}

extern "C" void kernel_launch(void* const* d_in, const int* in_sizes, int n_in,
                              void* d_out, int out_size, void* d_ws, size_t ws_size,
                              hipStream_t stream) {
    const float* params = (const float*)d_in[0];
    const float* points = (const float*)d_in[1];
    const float* dirs   = (const float*)d_in[2];
    float* out = (float*)d_out;
    dim3 grid(BLOCKS_PER_BATCH, NB);
    nerf_mlp_kernel<<<grid, 256, 0, stream>>>(params, points, dirs, out);
}